// Round 8
// baseline (168.318 us; speedup 1.0000x reference)
//
#include <hip/hip_runtime.h>
#include <hip/hip_bf16.h>

#define N_NODES 50000
#define N_EDGES 800000
#define D 128
#define SLOTS 64
#define NTILES 782  // ceil(50000/64)

typedef __attribute__((ext_vector_type(8))) short short8v;
typedef __attribute__((ext_vector_type(4))) float f32x4;

// ---------------------------------------------------------------------------
// ws layout: cnt[N]i32 | ss[N*64]u16 | xcs[8][N][16]bf16 | acs[8][N][16]bf16 |
//            Wt1[128*256]bf16 | Wt2[128*128]bf16      (~32.4 MB)
// xcs/acs slice s holds global cols [s*16, s*16+16) — 3.2 MB per slice.
// ---------------------------------------------------------------------------

__device__ __forceinline__ unsigned short f32_to_bf16_rn(float f) {
    unsigned int u = __float_as_uint(f);
    unsigned int r = (u + 0x7fffu + ((u >> 16) & 1u)) >> 16;
    return (unsigned short)r;
}
__device__ __forceinline__ unsigned int pack2(float a, float b) {
    return (unsigned int)f32_to_bf16_rn(a) |
           ((unsigned int)f32_to_bf16_rn(b) << 16);
}
__device__ __forceinline__ float bflo(unsigned int w) {
    return __uint_as_float(w << 16);
}
__device__ __forceinline__ float bfhi(unsigned int w) {
    return __uint_as_float(w & 0xffff0000u);
}

// 1) fill: u16 padded-CSR (atomic bump). Wt transposes appended (tiny).
__global__ __launch_bounds__(256) void fill_kernel(
    const int* __restrict__ ei, const float* __restrict__ W1,
    const float* __restrict__ W2, int* __restrict__ cnt,
    unsigned short* __restrict__ ss, unsigned short* __restrict__ Wt1,
    unsigned short* __restrict__ Wt2) {
    int tid = blockIdx.x * 256 + threadIdx.x;
    if (tid < N_EDGES) {
        int dst = ei[N_EDGES + tid];
        int pos = atomicAdd(&cnt[dst], 1);
        if (pos < SLOTS)
            ss[(size_t)dst * SLOTS + pos] = (unsigned short)ei[tid];
    }
    int t2 = tid - N_EDGES;
    if (t2 >= 0 && t2 < 128 * 256) {
        int n = t2 >> 8, k = t2 & 255;
        Wt1[t2] = f32_to_bf16_rn(W1[k * 128 + n]);
    }
    int t3 = t2 - 128 * 256;
    if (t3 >= 0 && t3 < 128 * 128) {
        int n = t3 >> 7, k = t3 & 127;
        Wt2[t3] = f32_to_bf16_rn(W2[k * 128 + n]);
    }
}

// 2) prep: x (f32 row-major) -> column-sliced bf16 xcs[8][N][16].
//    Thread reads one 128B half-row (32 f32), writes 2 slices x 32B.
__global__ __launch_bounds__(256) void prep_kernel(
    const float* __restrict__ x, unsigned short* __restrict__ xcs) {
    int n = blockIdx.x * 256 + threadIdx.x;
    int cp = blockIdx.y;  // 0..3 -> cols [cp*32, cp*32+32)
    if (n >= N_NODES) return;
    const float4* p = reinterpret_cast<const float4*>(x + (size_t)n * D + cp * 32);
    float4 v0 = p[0], v1 = p[1], v2 = p[2], v3 = p[3];
    float4 w0 = p[4], w1 = p[5], w2 = p[6], w3 = p[7];
    uint4 a0 = make_uint4(pack2(v0.x, v0.y), pack2(v0.z, v0.w),
                          pack2(v1.x, v1.y), pack2(v1.z, v1.w));
    uint4 a1 = make_uint4(pack2(v2.x, v2.y), pack2(v2.z, v2.w),
                          pack2(v3.x, v3.y), pack2(v3.z, v3.w));
    uint4 b0 = make_uint4(pack2(w0.x, w0.y), pack2(w0.z, w0.w),
                          pack2(w1.x, w1.y), pack2(w1.z, w1.w));
    uint4 b1 = make_uint4(pack2(w2.x, w2.y), pack2(w2.z, w2.w),
                          pack2(w3.x, w3.y), pack2(w3.z, w3.w));
    unsigned short* da = xcs + ((size_t)(2 * cp) * N_NODES + n) * 16;
    unsigned short* db = xcs + ((size_t)(2 * cp + 1) * N_NODES + n) * 16;
    reinterpret_cast<uint4*>(da)[0] = a0;
    reinterpret_cast<uint4*>(da)[1] = a1;
    reinterpret_cast<uint4*>(db)[0] = b0;
    reinterpret_cast<uint4*>(db)[1] = b1;
}

// 3) aggregate, XCD-sliced: block b -> slice b&7 (XCD-local 3.2MB table).
//    8-lane group owns one dst row-slice; per edge the group reads 32B.
__global__ __launch_bounds__(256) void aggregate_kernel(
    const unsigned short* __restrict__ xcs, const int* __restrict__ cnt,
    const unsigned short* __restrict__ ss, unsigned short* __restrict__ acs) {
    const int slice = blockIdx.x & 7;
    const int chunk = blockIdx.x >> 3;  // 0..1562, 32 rows each
    const int tid = threadIdx.x;
    const int lane = tid & 63;
    const int wv = tid >> 6;
    const int grp = lane >> 3;
    const int l8 = lane & 7;
    const int gb = lane & ~7;
    const int row = chunk * 32 + wv * 8 + grp;
    if (row >= N_NODES) return;
    int dg = __builtin_nontemporal_load(cnt + row);
    if (dg > SLOTS) dg = SLOTS;
    const unsigned short* sp = ss + (size_t)row * SLOTS;
    const unsigned short* xs = xcs + (size_t)slice * N_NODES * 16;
    float fx = 0.0f, fy = 0.0f;
    for (int j = 0; j < dg; j += 8) {
        int idv = 0;
        if (j + l8 < dg) idv = (int)__builtin_nontemporal_load(sp + j + l8);
        int m = dg - j;
        if (m > 8) m = 8;
        for (int k = 0; k < m; ++k) {
            int s = __shfl(idv, gb + k);
            unsigned int g =
                reinterpret_cast<const unsigned int*>(xs + (size_t)s * 16)[l8];
            fx += bflo(g);
            fy += bfhi(g);
        }
    }
    const float inv = 1.0f / fmaxf((float)dg, 1.0f);
    reinterpret_cast<unsigned int*>(acs +
                                    ((size_t)slice * N_NODES + row) * 16)[l8] =
        pack2(fx * inv, fy * inv);
}

// 4) MLP: weights staged once per block into swizzled LDS (round-7 validated);
//    A-fragments read from the sliced xcs/acs layouts.
__global__ __launch_bounds__(256, 1) void mlp_kernel(
    const unsigned short* __restrict__ xcs, const unsigned short* __restrict__ acs,
    const unsigned short* __restrict__ Wt1,
    const unsigned short* __restrict__ Wt2, const float* __restrict__ b1,
    const float* __restrict__ b2, float* __restrict__ out) {
    __shared__ unsigned char w1s[65536];    // Wt1 [128][256]bf16
    __shared__ unsigned char w2s[32768];    // Wt2 [128][128]bf16
    __shared__ unsigned char h1t[4][4096];  // per-wave h1 tile [16][128]bf16

    const int tid = threadIdx.x;
    for (int i = tid; i < 4096; i += 256) {
        unsigned o = (unsigned)i * 16;
        uint4 v = reinterpret_cast<const uint4*>(Wt1)[i];
        *reinterpret_cast<uint4*>(w1s + (o ^ (((o >> 9) & 7u) << 4))) = v;
    }
    for (int i = tid; i < 2048; i += 256) {
        unsigned o = (unsigned)i * 16;
        uint4 v = reinterpret_cast<const uint4*>(Wt2)[i];
        *reinterpret_cast<uint4*>(w2s + (o ^ (((o >> 8) & 7u) << 4))) = v;
    }

    const int lane = tid & 63;
    const int wv = tid >> 6;
    const int rloc = lane & 15;
    const int kseg = lane >> 4;
    const unsigned rswz = (unsigned)((rloc & 7) << 4);
    unsigned char* my = h1t[wv];

    float bias1[8], bias2[8];
#pragma unroll
    for (int ct = 0; ct < 8; ++ct) {
        bias1[ct] = b1[ct * 16 + rloc];
        bias2[ct] = b2[ct * 16 + rloc];
    }
    __syncthreads();

    const int soff = (kseg & 1) * 8;  // within-slice col offset
    for (int tile = blockIdx.x; tile < NTILES; tile += gridDim.x) {
        const int rbase = tile * 64 + wv * 16;
        int arow = rbase + rloc;
        if (arow >= N_NODES) arow = N_NODES - 1;

        // ---- layer 1: A from sliced xcs/acs, B from w1s ----
        short8v a[8];
#pragma unroll
        for (int kk = 0; kk < 8; ++kk) {
            const unsigned short* base = (kk < 4) ? xcs : acs;
            const int sl = ((kk & 3) * 2) + (kseg >> 1);
            a[kk] = *reinterpret_cast<const short8v*>(
                base + ((size_t)sl * N_NODES + arow) * 16 + soff);
        }
        f32x4 acc[8];
#pragma unroll
        for (int ct = 0; ct < 8; ++ct) acc[ct] = (f32x4){0.f, 0.f, 0.f, 0.f};
#pragma unroll
        for (int kk = 0; kk < 8; ++kk) {
#pragma unroll
            for (int ct = 0; ct < 8; ++ct) {
                unsigned off = (unsigned)((ct * 16 + rloc) * 512 + kk * 64 + kseg * 16);
                short8v b = *reinterpret_cast<const short8v*>(w1s + (off ^ rswz));
                acc[ct] = __builtin_amdgcn_mfma_f32_16x16x32_bf16(a[kk], b, acc[ct], 0, 0, 0);
            }
        }
#pragma unroll
        for (int ct = 0; ct < 8; ++ct) {
#pragma unroll
            for (int r = 0; r < 4; ++r) {
                int lrow = kseg * 4 + r;
                float v = fmaxf(acc[ct][r] + bias1[ct], 0.0f);
                unsigned off = (unsigned)(lrow * 256 + (ct * 16 + rloc) * 2);
                *reinterpret_cast<unsigned short*>(
                    my + (off ^ ((unsigned)((lrow & 7) << 4)))) = f32_to_bf16_rn(v);
            }
        }
        __syncthreads();

        // ---- layer 2: A from h1 tile, B from w2s ----
        short8v a2[4];
#pragma unroll
        for (int kk = 0; kk < 4; ++kk) {
            unsigned off = (unsigned)(rloc * 256 + kk * 64 + kseg * 16);
            a2[kk] = *reinterpret_cast<const short8v*>(my + (off ^ rswz));
        }
        f32x4 acc2[8];
#pragma unroll
        for (int ct = 0; ct < 8; ++ct) acc2[ct] = (f32x4){0.f, 0.f, 0.f, 0.f};
#pragma unroll
        for (int kk = 0; kk < 4; ++kk) {
#pragma unroll
            for (int ct = 0; ct < 8; ++ct) {
                unsigned off = (unsigned)((ct * 16 + rloc) * 256 + kk * 64 + kseg * 16);
                short8v b = *reinterpret_cast<const short8v*>(w2s + (off ^ rswz));
                acc2[ct] = __builtin_amdgcn_mfma_f32_16x16x32_bf16(a2[kk], b, acc2[ct], 0, 0, 0);
            }
        }
        const int orow0 = rbase + kseg * 4;
#pragma unroll
        for (int ct = 0; ct < 8; ++ct) {
#pragma unroll
            for (int r = 0; r < 4; ++r) {
                int row = orow0 + r;
                if (row < N_NODES) {
                    out[(size_t)row * 128 + ct * 16 + rloc] =
                        fmaxf(acc2[ct][r] + bias2[ct], 0.0f);
                }
            }
        }
        __syncthreads();
    }
}

extern "C" void kernel_launch(void* const* d_in, const int* in_sizes, int n_in,
                              void* d_out, int out_size, void* d_ws,
                              size_t ws_size, hipStream_t stream) {
    const float* node_feat = (const float*)d_in[0];
    const int* ei = (const int*)d_in[1];
    const float* W1 = (const float*)d_in[2];
    const float* b1 = (const float*)d_in[3];
    const float* W2 = (const float*)d_in[4];
    const float* b2 = (const float*)d_in[5];
    float* out = (float*)d_out;

    int* cnt = (int*)d_ws;
    unsigned short* ss = (unsigned short*)(cnt + N_NODES);
    unsigned short* xcs = ss + (size_t)N_NODES * SLOTS;
    unsigned short* acs = xcs + (size_t)8 * N_NODES * 16;
    unsigned short* Wt1 = acs + (size_t)8 * N_NODES * 16;
    unsigned short* Wt2 = Wt1 + 128 * 256;

    const int fill_threads = N_EDGES + 128 * 256 + 128 * 128;

    hipMemsetAsync(cnt, 0, N_NODES * sizeof(int), stream);
    fill_kernel<<<(fill_threads + 255) / 256, 256, 0, stream>>>(
        ei, W1, W2, cnt, ss, Wt1, Wt2);
    {
        dim3 g((N_NODES + 255) / 256, 4);
        prep_kernel<<<g, 256, 0, stream>>>(node_feat, xcs);
    }
    aggregate_kernel<<<1563 * 8, 256, 0, stream>>>(xcs, cnt, ss, acs);
    mlp_kernel<<<256, 256, 0, stream>>>(xcs, acs, Wt1, Wt2, b1, b2, out);
}

// Round 9
// 126.512 us; speedup vs baseline: 1.3305x; 1.3305x over previous
//
#include <hip/hip_runtime.h>
#include <hip/hip_bf16.h>

#define N_NODES 50000
#define N_EDGES 800000
#define D 128
#define SLOTS 64
#define NTILES 782  // ceil(50000/64)

typedef __attribute__((ext_vector_type(8))) short short8v;
typedef __attribute__((ext_vector_type(4))) float f32x4;

// ---------------------------------------------------------------------------
// ws layout: cnt[N]i32 | ss[N*64]u16 | xb[N*128]bf16 | ab[N*128]bf16 |
//            Wt1[128*256]bf16 | Wt2[128*128]bf16      (~32.4 MB)
// ---------------------------------------------------------------------------

__device__ __forceinline__ unsigned short f32_to_bf16_rn(float f) {
    unsigned int u = __float_as_uint(f);
    unsigned int r = (u + 0x7fffu + ((u >> 16) & 1u)) >> 16;
    return (unsigned short)r;
}
__device__ __forceinline__ unsigned int pack2(float a, float b) {
    return (unsigned int)f32_to_bf16_rn(a) |
           ((unsigned int)f32_to_bf16_rn(b) << 16);
}
__device__ __forceinline__ float bflo(unsigned int w) {
    return __uint_as_float(w << 16);
}
__device__ __forceinline__ float bfhi(unsigned int w) {
    return __uint_as_float(w & 0xffff0000u);
}

// 1) fill: u16 padded-CSR (atomic bump) + weight transposes (round-8 validated)
__global__ __launch_bounds__(256) void fill_kernel(
    const int* __restrict__ ei, const float* __restrict__ W1,
    const float* __restrict__ W2, int* __restrict__ cnt,
    unsigned short* __restrict__ ss, unsigned short* __restrict__ Wt1,
    unsigned short* __restrict__ Wt2) {
    int tid = blockIdx.x * 256 + threadIdx.x;
    if (tid < N_EDGES) {
        int dst = ei[N_EDGES + tid];
        int pos = atomicAdd(&cnt[dst], 1);
        if (pos < SLOTS)
            ss[(size_t)dst * SLOTS + pos] = (unsigned short)ei[tid];
    }
    int t2 = tid - N_EDGES;
    if (t2 >= 0 && t2 < 128 * 256) {
        int n = t2 >> 8, k = t2 & 255;
        Wt1[t2] = f32_to_bf16_rn(W1[k * 128 + n]);
    }
    int t3 = t2 - 128 * 256;
    if (t3 >= 0 && t3 < 128 * 128) {
        int n = t3 >> 7, k = t3 & 127;
        Wt2[t3] = f32_to_bf16_rn(W2[k * 128 + n]);
    }
}

// 2) prep: xb = bf16(node_feat), row-major (round-6/7 validated layout)
__global__ __launch_bounds__(256) void prep_kernel(
    const float* __restrict__ x, unsigned short* __restrict__ xb) {
    const int XBW = N_NODES * D / 8;  // 800000
    int tid = blockIdx.x * 256 + threadIdx.x;
    if (tid >= XBW) return;
    const float4* p = reinterpret_cast<const float4*>(x + (size_t)tid * 8);
    float4 v0 = p[0], v1 = p[1];
    uint4 o;
    o.x = pack2(v0.x, v0.y);
    o.y = pack2(v0.z, v0.w);
    o.z = pack2(v1.x, v1.y);
    o.w = pack2(v1.z, v1.w);
    *reinterpret_cast<uint4*>(xb + (size_t)tid * 8) = o;
}

// 3) aggregate: one wave per dst row (round-6-validated shape). Lane owns
//    cols 2*lane, 2*lane+1; edges sequential, 4-unrolled; wave-uniform u16
//    id loads from the padded CSR row.
__global__ __launch_bounds__(256) void aggregate_kernel(
    const unsigned short* __restrict__ xb, const int* __restrict__ cnt,
    const unsigned short* __restrict__ ss, unsigned short* __restrict__ ab) {
    const int lane = threadIdx.x & 63;
    const int row = blockIdx.x * 4 + (threadIdx.x >> 6);  // grid = 12500 exact
    int dg = cnt[row];
    if (dg > SLOTS) dg = SLOTS;
    const unsigned short* sp = ss + (size_t)row * SLOTS;
    float fx = 0.0f, fy = 0.0f;
    int j = 0;
    for (; j + 4 <= dg; j += 4) {
        int s0 = sp[j + 0];
        int s1 = sp[j + 1];
        int s2 = sp[j + 2];
        int s3 = sp[j + 3];
        unsigned int g0 = reinterpret_cast<const unsigned int*>(xb + (size_t)s0 * D)[lane];
        unsigned int g1 = reinterpret_cast<const unsigned int*>(xb + (size_t)s1 * D)[lane];
        unsigned int g2 = reinterpret_cast<const unsigned int*>(xb + (size_t)s2 * D)[lane];
        unsigned int g3 = reinterpret_cast<const unsigned int*>(xb + (size_t)s3 * D)[lane];
        fx += bflo(g0) + bflo(g1) + bflo(g2) + bflo(g3);
        fy += bfhi(g0) + bfhi(g1) + bfhi(g2) + bfhi(g3);
    }
    for (; j < dg; ++j) {
        int s0 = sp[j];
        unsigned int g0 = reinterpret_cast<const unsigned int*>(xb + (size_t)s0 * D)[lane];
        fx += bflo(g0);
        fy += bfhi(g0);
    }
    const float inv = 1.0f / fmaxf((float)dg, 1.0f);
    reinterpret_cast<unsigned int*>(ab + (size_t)row * D)[lane] =
        pack2(fx * inv, fy * inv);
}

// 4) MLP: weights staged once per block into swizzled LDS (round-7 validated).
__global__ __launch_bounds__(256, 1) void mlp_kernel(
    const unsigned short* __restrict__ xb, const unsigned short* __restrict__ ab,
    const unsigned short* __restrict__ Wt1,
    const unsigned short* __restrict__ Wt2, const float* __restrict__ b1,
    const float* __restrict__ b2, float* __restrict__ out) {
    __shared__ unsigned char w1s[65536];    // Wt1 [128][256]bf16
    __shared__ unsigned char w2s[32768];    // Wt2 [128][128]bf16
    __shared__ unsigned char h1t[4][4096];  // per-wave h1 tile [16][128]bf16

    const int tid = threadIdx.x;
    for (int i = tid; i < 4096; i += 256) {
        unsigned o = (unsigned)i * 16;
        uint4 v = reinterpret_cast<const uint4*>(Wt1)[i];
        *reinterpret_cast<uint4*>(w1s + (o ^ (((o >> 9) & 7u) << 4))) = v;
    }
    for (int i = tid; i < 2048; i += 256) {
        unsigned o = (unsigned)i * 16;
        uint4 v = reinterpret_cast<const uint4*>(Wt2)[i];
        *reinterpret_cast<uint4*>(w2s + (o ^ (((o >> 8) & 7u) << 4))) = v;
    }

    const int lane = tid & 63;
    const int wv = tid >> 6;
    const int rloc = lane & 15;
    const int kseg = lane >> 4;
    const unsigned rswz = (unsigned)((rloc & 7) << 4);
    unsigned char* my = h1t[wv];

    float bias1[8], bias2[8];
#pragma unroll
    for (int ct = 0; ct < 8; ++ct) {
        bias1[ct] = b1[ct * 16 + rloc];
        bias2[ct] = b2[ct * 16 + rloc];
    }
    __syncthreads();

    for (int tile = blockIdx.x; tile < NTILES; tile += gridDim.x) {
        const int rbase = tile * 64 + wv * 16;
        int arow = rbase + rloc;
        if (arow >= N_NODES) arow = N_NODES - 1;

        // ---- layer 1: A from global (xb|ab), B from w1s ----
        short8v a[8];
#pragma unroll
        for (int kk = 0; kk < 8; ++kk) {
            const unsigned short* ap =
                (kk < 4) ? xb + (size_t)arow * D + kk * 32 + kseg * 8
                         : ab + (size_t)arow * D + (kk - 4) * 32 + kseg * 8;
            a[kk] = *reinterpret_cast<const short8v*>(ap);
        }
        f32x4 acc[8];
#pragma unroll
        for (int ct = 0; ct < 8; ++ct) acc[ct] = (f32x4){0.f, 0.f, 0.f, 0.f};
#pragma unroll
        for (int kk = 0; kk < 8; ++kk) {
#pragma unroll
            for (int ct = 0; ct < 8; ++ct) {
                unsigned off = (unsigned)((ct * 16 + rloc) * 512 + kk * 64 + kseg * 16);
                short8v b = *reinterpret_cast<const short8v*>(w1s + (off ^ rswz));
                acc[ct] = __builtin_amdgcn_mfma_f32_16x16x32_bf16(a[kk], b, acc[ct], 0, 0, 0);
            }
        }
#pragma unroll
        for (int ct = 0; ct < 8; ++ct) {
#pragma unroll
            for (int r = 0; r < 4; ++r) {
                int lrow = kseg * 4 + r;
                float v = fmaxf(acc[ct][r] + bias1[ct], 0.0f);
                unsigned off = (unsigned)(lrow * 256 + (ct * 16 + rloc) * 2);
                *reinterpret_cast<unsigned short*>(
                    my + (off ^ ((unsigned)((lrow & 7) << 4)))) = f32_to_bf16_rn(v);
            }
        }
        __syncthreads();

        // ---- layer 2: A from h1 tile, B from w2s ----
        short8v a2[4];
#pragma unroll
        for (int kk = 0; kk < 4; ++kk) {
            unsigned off = (unsigned)(rloc * 256 + kk * 64 + kseg * 16);
            a2[kk] = *reinterpret_cast<const short8v*>(my + (off ^ rswz));
        }
        f32x4 acc2[8];
#pragma unroll
        for (int ct = 0; ct < 8; ++ct) acc2[ct] = (f32x4){0.f, 0.f, 0.f, 0.f};
#pragma unroll
        for (int kk = 0; kk < 4; ++kk) {
#pragma unroll
            for (int ct = 0; ct < 8; ++ct) {
                unsigned off = (unsigned)((ct * 16 + rloc) * 256 + kk * 64 + kseg * 16);
                short8v b = *reinterpret_cast<const short8v*>(w2s + (off ^ rswz));
                acc2[ct] = __builtin_amdgcn_mfma_f32_16x16x32_bf16(a2[kk], b, acc2[ct], 0, 0, 0);
            }
        }
        const int orow0 = rbase + kseg * 4;
#pragma unroll
        for (int ct = 0; ct < 8; ++ct) {
#pragma unroll
            for (int r = 0; r < 4; ++r) {
                int row = orow0 + r;
                if (row < N_NODES) {
                    out[(size_t)row * 128 + ct * 16 + rloc] =
                        fmaxf(acc2[ct][r] + bias2[ct], 0.0f);
                }
            }
        }
        __syncthreads();
    }
}

extern "C" void kernel_launch(void* const* d_in, const int* in_sizes, int n_in,
                              void* d_out, int out_size, void* d_ws,
                              size_t ws_size, hipStream_t stream) {
    const float* node_feat = (const float*)d_in[0];
    const int* ei = (const int*)d_in[1];
    const float* W1 = (const float*)d_in[2];
    const float* b1 = (const float*)d_in[3];
    const float* W2 = (const float*)d_in[4];
    const float* b2 = (const float*)d_in[5];
    float* out = (float*)d_out;

    int* cnt = (int*)d_ws;
    unsigned short* ss = (unsigned short*)(cnt + N_NODES);
    unsigned short* xb = ss + (size_t)N_NODES * SLOTS;
    unsigned short* ab = xb + (size_t)N_NODES * D;
    unsigned short* Wt1 = ab + (size_t)N_NODES * D;
    unsigned short* Wt2 = Wt1 + 128 * 256;

    const int fill_threads = N_EDGES + 128 * 256 + 128 * 128;

    hipMemsetAsync(cnt, 0, N_NODES * sizeof(int), stream);
    fill_kernel<<<(fill_threads + 255) / 256, 256, 0, stream>>>(
        ei, W1, W2, cnt, ss, Wt1, Wt2);
    prep_kernel<<<(N_NODES * D / 8 + 255) / 256, 256, 0, stream>>>(node_feat, xb);
    aggregate_kernel<<<N_NODES / 4, 256, 0, stream>>>(xb, cnt, ss, ab);
    mlp_kernel<<<256, 256, 0, stream>>>(xb, ab, Wt1, Wt2, b1, b2, out);
}